// Round 10
// baseline (3838.354 us; speedup 1.0000x reference)
//
#include <hip/hip_runtime.h>
#include <stdint.h>

// Voxelization (hard), matching the JAX reference exactly.
// GRID = (1024,1024,40), VOXEL=(0.1,0.1,0.2), RANGE_LO=(-51.2,-51.2,-5.0)
// MAX_POINTS=10, MAX_VOXELS=120000.
//
// Open-addressing 64-bit hash table (2^22 slots, 33.5 MB).
// Slot = (min_point_idx << 26) | lin, then (bit63 | rank << 26 | lin) for
// surviving voxels (rank < MAXV).
//
// Structure (post-mortem of measured R4/R7/R8):
//  * k1 CAS-first insert (stable 52us, FETCH 75->11.7MB win kept).
//  * creator detection by VERIFY-READ (R4 style) — the R7/R8 table-sweep +
//    bitmask atomicOr scatter was the regression (+35us).
//  * verify only the first NB1CAP*256=256K points (k2a1): creator count is
//    monotone in index and hits MAXV by ~138K, so later creators can never
//    survive. Guarded k2a2/k2b2 (device-flag early-exit) keep exactness for
//    arbitrary inputs.
//  * d_out memset restored (coalesced zeros); k4 writes only real rows —
//    R8's per-thread zero-fill was uncoalesced (+25us).

#define GXD 1024
#define GYD 1024
#define GZD 40
#define GYZ (GYD * GZD)          // 40960
#define MAXV 120000
#define MAXP 10
#define CAP 16

#define HBITS 22
#define HSIZE (1u << HBITS)      // 4,194,304 slots * 8B = 33.5 MB
#define HMASK (HSIZE - 1u)
#define KEYMASK ((1ull << 26) - 1ull)
#define EMPTY64 0xFFFFFFFFFFFFFFFFull
#define NB1CAP 1024              // verify blocks in phase 1 (256K points)

__device__ __forceinline__ unsigned hash_lin(unsigned l) {
    return (l * 2654435761u) >> (32 - HBITS);
}

// K1: per-point voxel coord + CAS-first hash insert with min-idx semantics.
__global__ void k1_assign(const float* __restrict__ pts, int n,
                          int* __restrict__ lin_arr, int* __restrict__ slot_arr,
                          unsigned long long* __restrict__ table) {
    int i = blockIdx.x * blockDim.x + threadIdx.x;
    if (i >= n) return;
    float x = pts[(size_t)i * 5 + 0];
    float y = pts[(size_t)i * 5 + 1];
    float z = pts[(size_t)i * 5 + 2];
    // exact reference arithmetic: f32 sub, IEEE f32 div, floorf, cast
    int cx = (int)floorf((x - (-51.2f)) / 0.1f);
    int cy = (int)floorf((y - (-51.2f)) / 0.1f);
    int cz = (int)floorf((z - (-5.0f)) / 0.2f);
    bool valid = (cx >= 0) & (cx < GXD) & (cy >= 0) & (cy < GYD) & (cz >= 0) & (cz < GZD);
    if (!valid) { lin_arr[i] = -1; slot_arr[i] = -1; return; }
    unsigned l = (unsigned)(cx * GYZ + cy * GZD + cz);
    lin_arr[i] = (int)l;
    unsigned long long want = ((unsigned long long)(unsigned)i << 26) | (unsigned long long)l;
    unsigned s = hash_lin(l);
    while (true) {
        // CAS-first: one atomic round-trip resolves the empty-slot path.
        unsigned long long cur = atomicCAS(&table[s], EMPTY64, want);
        if (cur == EMPTY64) break;                       // inserted fresh
        if ((cur & KEYMASK) == (unsigned long long)l) {  // voxel exists
            // slot idx only decreases; stale reads only show LARGER idx,
            // so skipping the atomic when cur_idx < i is safe. atomicMin
            // result unused -> fire-and-forget (no wait).
            if ((cur >> 26) > (unsigned long long)(unsigned)i)
                atomicMin(&table[s], want);
            break;
        }
        s = (s + 1) & HMASK;                             // collision: probe on
    }
    slot_arr[i] = (int)s;
}

// Shared body: verify-read creator flags for one 256-point block `b`.
__device__ __forceinline__ void mark_block(int b, int n,
                                           const int* __restrict__ slot_arr,
                                           const unsigned long long* __restrict__ table,
                                           unsigned long long* __restrict__ flagWords,
                                           int* __restrict__ blockCnt) {
    int i = b * 256 + threadIdx.x;
    bool first = false;
    if (i < n) {
        int s = slot_arr[i];
        if (s >= 0) {
            unsigned long long v = table[s];
            first = ((v >> 26) == (unsigned long long)(unsigned)i);
        }
    }
    unsigned long long m = __ballot(first);
    __shared__ int ws[4];
    int lane = threadIdx.x & 63, w = threadIdx.x >> 6;
    if (lane == 0) { flagWords[(size_t)b * 4 + w] = m; ws[w] = __popcll(m); }
    __syncthreads();
    if (threadIdx.x == 0)
        blockCnt[b] = ws[0] + ws[1] + ws[2] + ws[3];
}

// K2a1: verify-read creator flags for the first nb1 blocks.
__global__ void k2a1_mark(int n, const int* __restrict__ slot_arr,
                          const unsigned long long* __restrict__ table,
                          unsigned long long* __restrict__ flagWords,
                          int* __restrict__ blockCnt) {
    mark_block(blockIdx.x, n, slot_arr, table, flagWords, blockCnt);
}

// K2b1: scan blockCnt[0..nb1) -> blockOff, total1; need2 = (total1<MAXV && nb>nb1).
__global__ void k2b1_scan(int nb1, int nb, const int* __restrict__ blockCnt,
                          int* __restrict__ blockOff, int* __restrict__ meta) {
    __shared__ int tsum[256];
    __shared__ int toff[256];
    int t = threadIdx.x;
    int chunk = (nb1 + 255) / 256;
    int lo = t * chunk;
    int hi = lo + chunk; if (hi > nb1) hi = nb1;
    int s = 0;
    for (int j = lo; j < hi; ++j) s += blockCnt[j];
    tsum[t] = s;
    __syncthreads();
    if (t == 0) {
        int acc = 0;
        for (int j = 0; j < 256; ++j) { int v = tsum[j]; toff[j] = acc; acc += v; }
        meta[0] = acc;                                   // total1
        meta[1] = (acc < MAXV && nb > nb1) ? 1 : 0;      // need2
    }
    __syncthreads();
    int off = toff[t];
    for (int j = lo; j < hi; ++j) { blockOff[j] = off; off += blockCnt[j]; }
}

// K2a2: phase-2 verify (blocks nb1..nb) — runs only if need2 (cap not reached).
__global__ void k2a2_mark(int n, int nb1, const int* __restrict__ meta,
                          const int* __restrict__ slot_arr,
                          const unsigned long long* __restrict__ table,
                          unsigned long long* __restrict__ flagWords,
                          int* __restrict__ blockCnt) {
    if (meta[1] == 0) return;                            // cap reached: skip
    mark_block(blockIdx.x + nb1, n, slot_arr, table, flagWords, blockCnt);
}

// K2b2: finalize. If need2: full rescan of blockCnt[0..nb) -> blockOff + vn.
// Else: vn = min(total1, MAXV) (tail flagWords are zero -> no tail creators).
__global__ void k2b2_scan(int nb, const int* __restrict__ meta,
                          const int* __restrict__ blockCnt,
                          int* __restrict__ blockOff,
                          float* __restrict__ voxel_num_out) {
    if (meta[1] == 0) {
        if (threadIdx.x == 0) {
            int v = meta[0]; if (v > MAXV) v = MAXV;
            *voxel_num_out = (float)v;
        }
        return;
    }
    __shared__ int tsum[256];
    __shared__ int toff[256];
    int t = threadIdx.x;
    int chunk = (nb + 255) / 256;
    int lo = t * chunk;
    int hi = lo + chunk; if (hi > nb) hi = nb;
    int s = 0;
    for (int j = lo; j < hi; ++j) s += blockCnt[j];
    tsum[t] = s;
    __syncthreads();
    if (t == 0) {
        int acc = 0;
        for (int j = 0; j < 256; ++j) { int v = tsum[j]; toff[j] = acc; acc += v; }
        int vn = acc < MAXV ? acc : MAXV;
        *voxel_num_out = (float)vn;
    }
    __syncthreads();
    int off = toff[t];
    for (int j = lo; j < hi; ++j) { blockOff[j] = off; off += blockCnt[j]; }
}

// K2c: creators compute rank from flag words; surviving creators (rank < MAXV)
// write (bit63 | rank<<26 | lin) into their own slot (unique owner -> plain
// store) and emit coors.
__global__ void k2c_rank(int n, const int* __restrict__ lin_arr,
                         const int* __restrict__ slot_arr,
                         const unsigned long long* __restrict__ flagWords,
                         const int* __restrict__ blockOff,
                         unsigned long long* __restrict__ table,
                         float* __restrict__ coors_out) {
    int i = blockIdx.x * blockDim.x + threadIdx.x;
    int lane = threadIdx.x & 63, w = threadIdx.x >> 6;
    unsigned long long m = flagWords[(size_t)blockIdx.x * 4 + w];
    __shared__ int ws[4];
    if (lane == 0) ws[w] = __popcll(m);
    __syncthreads();
    bool first = (i < n) && ((m >> lane) & 1ull);
    if (!first) return;
    int off = blockOff[blockIdx.x];
    for (int j = 0; j < w; ++j) off += ws[j];
    int rank = off + (int)__popcll(m & ((1ull << lane) - 1ull));
    if (rank >= MAXV) return;
    int l = lin_arr[i];
    int s = slot_arr[i];
    table[s] = (1ull << 63) | ((unsigned long long)(unsigned)rank << 26)
             | (unsigned long long)(unsigned)l;
    int cx = l / GYZ;
    int r = l - cx * GYZ;
    int cy = r / GZD;
    int cz = r - cy * GZD;
    coors_out[(size_t)rank * 3 + 0] = (float)cx;
    coors_out[(size_t)rank * 3 + 1] = (float)cy;
    coors_out[(size_t)rank * 3 + 2] = (float)cz;
}

// K3: ONE random table read per point; survived (bit63) -> append own index.
__global__ void k3_append(int n, const int* __restrict__ slot_arr,
                          const unsigned long long* __restrict__ table,
                          int* __restrict__ vcount, int* __restrict__ vlist) {
    int i = blockIdx.x * blockDim.x + threadIdx.x;
    if (i >= n) return;
    int s = slot_arr[i];
    if (s < 0) return;
    unsigned long long v = table[s];
    if (!(v >> 63)) return;
    int rank = (int)((v >> 26) & 0x1FFFFFull);
    int pos = atomicAdd(&vcount[rank], 1);
    if (pos < CAP) vlist[(size_t)rank * CAP + pos] = i;
}

// K4: per voxel: sort indices ascending (restores original-order slots), emit
// real rows only (d_out memset covers zeros / empty voxels).
__global__ void k4_emit(const float* __restrict__ pts,
                        const int* __restrict__ vcount,
                        const int* __restrict__ vlist,
                        float* __restrict__ vox_out, float* __restrict__ num_out,
                        int* __restrict__ ovflCnt, int* __restrict__ ovflList) {
    int v = blockIdx.x * blockDim.x + threadIdx.x;
    if (v >= MAXV) return;
    int cnt = vcount[v];
    if (cnt == 0) return;
    if (cnt > CAP) {
        int e = atomicAdd(ovflCnt, 1);
        if (e < 1024) ovflList[e] = v;
        return;
    }
    int idx[CAP];
    for (int j = 0; j < cnt; ++j) idx[j] = vlist[(size_t)v * CAP + j];
    for (int a = 1; a < cnt; ++a) {
        int key = idx[a];
        int b = a - 1;
        while (b >= 0 && idx[b] > key) { idx[b + 1] = idx[b]; --b; }
        idx[b + 1] = key;
    }
    int np = cnt < MAXP ? cnt : MAXP;
    num_out[v] = (float)np;
    for (int s = 0; s < np; ++s) {
        const float* p = pts + (size_t)idx[s] * 5;
        float* o = vox_out + ((size_t)v * MAXP + s) * 5;
        o[0] = p[0]; o[1] = p[1]; o[2] = p[2]; o[3] = p[3]; o[4] = p[4];
    }
}

// K5: exact fallback for >CAP-point voxels (expected empty): serial ordered rescan.
__global__ void k5_ovfl(const float* __restrict__ pts, int n,
                        const int* __restrict__ lin_arr,
                        const int* __restrict__ vcount,
                        const int* __restrict__ ovflCnt,
                        const int* __restrict__ ovflList,
                        const float* __restrict__ coors_out,
                        float* __restrict__ vox_out, float* __restrict__ num_out) {
    if (threadIdx.x != 0 || blockIdx.x != 0) return;
    int cnt = *ovflCnt;
    if (cnt > 1024) cnt = 1024;
    for (int e = 0; e < cnt; ++e) {
        int v = ovflList[e];
        int cx = (int)coors_out[(size_t)v * 3 + 0];
        int cy = (int)coors_out[(size_t)v * 3 + 1];
        int cz = (int)coors_out[(size_t)v * 3 + 2];
        int target = cx * GYZ + cy * GZD + cz;
        int found = 0;
        for (int i = 0; i < n && found < MAXP; ++i) {
            if (lin_arr[i] == target) {
                const float* p = pts + (size_t)i * 5;
                float* o = vox_out + ((size_t)v * MAXP + found) * 5;
                for (int c = 0; c < 5; ++c) o[c] = p[c];
                ++found;
            }
        }
        int np = vcount[v] < MAXP ? vcount[v] : MAXP;
        num_out[v] = (float)np;
    }
}

extern "C" void kernel_launch(void* const* d_in, const int* in_sizes, int n_in,
                              void* d_out, int out_size, void* d_ws, size_t ws_size,
                              hipStream_t stream) {
    const float* pts = (const float*)d_in[0];
    int n = in_sizes[0] / 5;
    int nb = (n + 255) / 256;
    int nb1 = nb < NB1CAP ? nb : NB1CAP;

    float* out = (float*)d_out;
    float* vox_out   = out;                       // [120000][10][5] = 6,000,000
    float* coors_out = out + 6000000;             // [120000][3]     =   360,000
    float* num_out   = out + 6360000;             // [120000]        =   120,000
    float* vn_out    = out + 6480000;             // scalar

    char* w = (char*)d_ws;
    unsigned long long* table = (unsigned long long*)w;  w += (size_t)HSIZE * 8; // 33.5 MB
    int* lin_arr   = (int*)w;               w += (size_t)n * 4;
    int* slot_arr  = (int*)w;               w += (size_t)n * 4;
    int* blockCnt  = (int*)w;               w += (size_t)nb * 4;
    int* blockOff  = (int*)w;               w += (size_t)nb * 4;
    int* vlist     = (int*)w;               w += (size_t)MAXV * CAP * 4;
    // zeroed region (one memset): flagWords + vcount + ovflCnt + meta
    unsigned long long* flagWords = (unsigned long long*)w; w += (size_t)nb * 4 * 8;
    int* vcount    = (int*)w;               w += (size_t)MAXV * 4;
    int* ovflCnt   = (int*)w;               w += 4;
    int* meta      = (int*)w;               w += 2 * 4;   // [total1, need2]
    int* ovflList  = (int*)w;               w += 1024 * 4;
    size_t zeroBytes = (size_t)nb * 4 * 8 + (size_t)MAXV * 4 + 4 + 8;

    hipMemsetAsync(d_out, 0, (size_t)out_size * 4, stream);
    hipMemsetAsync(table, 0xFF, (size_t)HSIZE * 8, stream);   // EMPTY64 sentinels
    hipMemsetAsync(flagWords, 0, zeroBytes, stream);

    k1_assign<<<nb, 256, 0, stream>>>(pts, n, lin_arr, slot_arr, table);
    k2a1_mark<<<nb1, 256, 0, stream>>>(n, slot_arr, table, flagWords, blockCnt);
    k2b1_scan<<<1, 256, 0, stream>>>(nb1, nb, blockCnt, blockOff, meta);
    if (nb > nb1) {
        k2a2_mark<<<nb - nb1, 256, 0, stream>>>(n, nb1, meta, slot_arr, table,
                                                flagWords, blockCnt);
    }
    k2b2_scan<<<1, 256, 0, stream>>>(nb, meta, blockCnt, blockOff, vn_out);
    k2c_rank<<<nb, 256, 0, stream>>>(n, lin_arr, slot_arr, flagWords, blockOff,
                                     table, coors_out);
    k3_append<<<nb, 256, 0, stream>>>(n, slot_arr, table, vcount, vlist);
    k4_emit<<<(MAXV + 255) / 256, 256, 0, stream>>>(pts, vcount, vlist, vox_out,
                                                    num_out, ovflCnt, ovflList);
    k5_ovfl<<<1, 64, 0, stream>>>(pts, n, lin_arr, vcount, ovflCnt, ovflList,
                                  coors_out, vox_out, num_out);
}

// Round 11
// 179.774 us; speedup vs baseline: 21.3510x; 21.3510x over previous
//
#include <hip/hip_runtime.h>
#include <stdint.h>

// Voxelization (hard), matching the JAX reference exactly.
// GRID = (1024,1024,40), VOXEL=(0.1,0.1,0.2), RANGE_LO=(-51.2,-51.2,-5.0)
// MAX_POINTS=10, MAX_VOXELS=120000.
//
// Open-addressing 64-bit hash table (2^22 slots, 33.5 MB).
// Slot = (min_point_idx << 26) | lin, then (bit63 | rank << 26 | lin) for
// surviving voxels (rank < MAXV).
//
// Structure (post-mortem of measured R4/R7/R8; R10 timing discarded as
// contended — counters identical to R8, no dispatch > 52us):
//  * k1 CAS-first insert (stable 52us, FETCH 75->11.7MB win kept).
//  * creator detection by VERIFY-READ (R4 style) — the R7/R8 table-sweep +
//    bitmask atomicOr scatter was the regression (+35us).
//  * verify only the first NB1CAP*256=256K points (k2a1): creator count is
//    monotone in index and hits MAXV by ~138K, so later creators can never
//    survive. Guarded k2a2/k2b2 (device-flag early-exit) keep exactness for
//    arbitrary inputs.
//  * d_out memset (coalesced zeros); k4 writes only real rows — R8's
//    per-thread zero-fill was uncoalesced (+25us).

#define GXD 1024
#define GYD 1024
#define GZD 40
#define GYZ (GYD * GZD)          // 40960
#define MAXV 120000
#define MAXP 10
#define CAP 16

#define HBITS 22
#define HSIZE (1u << HBITS)      // 4,194,304 slots * 8B = 33.5 MB
#define HMASK (HSIZE - 1u)
#define KEYMASK ((1ull << 26) - 1ull)
#define EMPTY64 0xFFFFFFFFFFFFFFFFull
#define NB1CAP 1024              // verify blocks in phase 1 (256K points)

__device__ __forceinline__ unsigned hash_lin(unsigned l) {
    return (l * 2654435761u) >> (32 - HBITS);
}

// K1: per-point voxel coord + CAS-first hash insert with min-idx semantics.
__global__ void k1_assign(const float* __restrict__ pts, int n,
                          int* __restrict__ lin_arr, int* __restrict__ slot_arr,
                          unsigned long long* __restrict__ table) {
    int i = blockIdx.x * blockDim.x + threadIdx.x;
    if (i >= n) return;
    float x = pts[(size_t)i * 5 + 0];
    float y = pts[(size_t)i * 5 + 1];
    float z = pts[(size_t)i * 5 + 2];
    // exact reference arithmetic: f32 sub, IEEE f32 div, floorf, cast
    int cx = (int)floorf((x - (-51.2f)) / 0.1f);
    int cy = (int)floorf((y - (-51.2f)) / 0.1f);
    int cz = (int)floorf((z - (-5.0f)) / 0.2f);
    bool valid = (cx >= 0) & (cx < GXD) & (cy >= 0) & (cy < GYD) & (cz >= 0) & (cz < GZD);
    if (!valid) { lin_arr[i] = -1; slot_arr[i] = -1; return; }
    unsigned l = (unsigned)(cx * GYZ + cy * GZD + cz);
    lin_arr[i] = (int)l;
    unsigned long long want = ((unsigned long long)(unsigned)i << 26) | (unsigned long long)l;
    unsigned s = hash_lin(l);
    while (true) {
        // CAS-first: one atomic round-trip resolves the empty-slot path.
        unsigned long long cur = atomicCAS(&table[s], EMPTY64, want);
        if (cur == EMPTY64) break;                       // inserted fresh
        if ((cur & KEYMASK) == (unsigned long long)l) {  // voxel exists
            // slot idx only decreases; stale reads only show LARGER idx,
            // so skipping the atomic when cur_idx < i is safe. atomicMin
            // result unused -> fire-and-forget (no wait).
            if ((cur >> 26) > (unsigned long long)(unsigned)i)
                atomicMin(&table[s], want);
            break;
        }
        s = (s + 1) & HMASK;                             // collision: probe on
    }
    slot_arr[i] = (int)s;
}

// Shared body: verify-read creator flags for one 256-point block `b`.
__device__ __forceinline__ void mark_block(int b, int n,
                                           const int* __restrict__ slot_arr,
                                           const unsigned long long* __restrict__ table,
                                           unsigned long long* __restrict__ flagWords,
                                           int* __restrict__ blockCnt) {
    int i = b * 256 + threadIdx.x;
    bool first = false;
    if (i < n) {
        int s = slot_arr[i];
        if (s >= 0) {
            unsigned long long v = table[s];
            first = ((v >> 26) == (unsigned long long)(unsigned)i);
        }
    }
    unsigned long long m = __ballot(first);
    __shared__ int ws[4];
    int lane = threadIdx.x & 63, w = threadIdx.x >> 6;
    if (lane == 0) { flagWords[(size_t)b * 4 + w] = m; ws[w] = __popcll(m); }
    __syncthreads();
    if (threadIdx.x == 0)
        blockCnt[b] = ws[0] + ws[1] + ws[2] + ws[3];
}

// K2a1: verify-read creator flags for the first nb1 blocks.
__global__ void k2a1_mark(int n, const int* __restrict__ slot_arr,
                          const unsigned long long* __restrict__ table,
                          unsigned long long* __restrict__ flagWords,
                          int* __restrict__ blockCnt) {
    mark_block(blockIdx.x, n, slot_arr, table, flagWords, blockCnt);
}

// K2b1: scan blockCnt[0..nb1) -> blockOff, total1; need2 = (total1<MAXV && nb>nb1).
__global__ void k2b1_scan(int nb1, int nb, const int* __restrict__ blockCnt,
                          int* __restrict__ blockOff, int* __restrict__ meta) {
    __shared__ int tsum[256];
    __shared__ int toff[256];
    int t = threadIdx.x;
    int chunk = (nb1 + 255) / 256;
    int lo = t * chunk;
    int hi = lo + chunk; if (hi > nb1) hi = nb1;
    int s = 0;
    for (int j = lo; j < hi; ++j) s += blockCnt[j];
    tsum[t] = s;
    __syncthreads();
    if (t == 0) {
        int acc = 0;
        for (int j = 0; j < 256; ++j) { int v = tsum[j]; toff[j] = acc; acc += v; }
        meta[0] = acc;                                   // total1
        meta[1] = (acc < MAXV && nb > nb1) ? 1 : 0;      // need2
    }
    __syncthreads();
    int off = toff[t];
    for (int j = lo; j < hi; ++j) { blockOff[j] = off; off += blockCnt[j]; }
}

// K2a2: phase-2 verify (blocks nb1..nb) — runs only if need2 (cap not reached).
__global__ void k2a2_mark(int n, int nb1, const int* __restrict__ meta,
                          const int* __restrict__ slot_arr,
                          const unsigned long long* __restrict__ table,
                          unsigned long long* __restrict__ flagWords,
                          int* __restrict__ blockCnt) {
    if (meta[1] == 0) return;                            // cap reached: skip
    mark_block(blockIdx.x + nb1, n, slot_arr, table, flagWords, blockCnt);
}

// K2b2: finalize. If need2: full rescan of blockCnt[0..nb) -> blockOff + vn.
// Else: vn = min(total1, MAXV) (tail flagWords are zero -> no tail creators).
__global__ void k2b2_scan(int nb, const int* __restrict__ meta,
                          const int* __restrict__ blockCnt,
                          int* __restrict__ blockOff,
                          float* __restrict__ voxel_num_out) {
    if (meta[1] == 0) {
        if (threadIdx.x == 0) {
            int v = meta[0]; if (v > MAXV) v = MAXV;
            *voxel_num_out = (float)v;
        }
        return;
    }
    __shared__ int tsum[256];
    __shared__ int toff[256];
    int t = threadIdx.x;
    int chunk = (nb + 255) / 256;
    int lo = t * chunk;
    int hi = lo + chunk; if (hi > nb) hi = nb;
    int s = 0;
    for (int j = lo; j < hi; ++j) s += blockCnt[j];
    tsum[t] = s;
    __syncthreads();
    if (t == 0) {
        int acc = 0;
        for (int j = 0; j < 256; ++j) { int v = tsum[j]; toff[j] = acc; acc += v; }
        int vn = acc < MAXV ? acc : MAXV;
        *voxel_num_out = (float)vn;
    }
    __syncthreads();
    int off = toff[t];
    for (int j = lo; j < hi; ++j) { blockOff[j] = off; off += blockCnt[j]; }
}

// K2c: creators compute rank from flag words; surviving creators (rank < MAXV)
// write (bit63 | rank<<26 | lin) into their own slot (unique owner -> plain
// store) and emit coors.
__global__ void k2c_rank(int n, const int* __restrict__ lin_arr,
                         const int* __restrict__ slot_arr,
                         const unsigned long long* __restrict__ flagWords,
                         const int* __restrict__ blockOff,
                         unsigned long long* __restrict__ table,
                         float* __restrict__ coors_out) {
    int i = blockIdx.x * blockDim.x + threadIdx.x;
    int lane = threadIdx.x & 63, w = threadIdx.x >> 6;
    unsigned long long m = flagWords[(size_t)blockIdx.x * 4 + w];
    __shared__ int ws[4];
    if (lane == 0) ws[w] = __popcll(m);
    __syncthreads();
    bool first = (i < n) && ((m >> lane) & 1ull);
    if (!first) return;
    int off = blockOff[blockIdx.x];
    for (int j = 0; j < w; ++j) off += ws[j];
    int rank = off + (int)__popcll(m & ((1ull << lane) - 1ull));
    if (rank >= MAXV) return;
    int l = lin_arr[i];
    int s = slot_arr[i];
    table[s] = (1ull << 63) | ((unsigned long long)(unsigned)rank << 26)
             | (unsigned long long)(unsigned)l;
    int cx = l / GYZ;
    int r = l - cx * GYZ;
    int cy = r / GZD;
    int cz = r - cy * GZD;
    coors_out[(size_t)rank * 3 + 0] = (float)cx;
    coors_out[(size_t)rank * 3 + 1] = (float)cy;
    coors_out[(size_t)rank * 3 + 2] = (float)cz;
}

// K3: ONE random table read per point; survived (bit63) -> append own index.
__global__ void k3_append(int n, const int* __restrict__ slot_arr,
                          const unsigned long long* __restrict__ table,
                          int* __restrict__ vcount, int* __restrict__ vlist) {
    int i = blockIdx.x * blockDim.x + threadIdx.x;
    if (i >= n) return;
    int s = slot_arr[i];
    if (s < 0) return;
    unsigned long long v = table[s];
    if (!(v >> 63)) return;
    int rank = (int)((v >> 26) & 0x1FFFFFull);
    int pos = atomicAdd(&vcount[rank], 1);
    if (pos < CAP) vlist[(size_t)rank * CAP + pos] = i;
}

// K4: per voxel: sort indices ascending (restores original-order slots), emit
// real rows only (d_out memset covers zeros / empty voxels).
__global__ void k4_emit(const float* __restrict__ pts,
                        const int* __restrict__ vcount,
                        const int* __restrict__ vlist,
                        float* __restrict__ vox_out, float* __restrict__ num_out,
                        int* __restrict__ ovflCnt, int* __restrict__ ovflList) {
    int v = blockIdx.x * blockDim.x + threadIdx.x;
    if (v >= MAXV) return;
    int cnt = vcount[v];
    if (cnt == 0) return;
    if (cnt > CAP) {
        int e = atomicAdd(ovflCnt, 1);
        if (e < 1024) ovflList[e] = v;
        return;
    }
    int idx[CAP];
    for (int j = 0; j < cnt; ++j) idx[j] = vlist[(size_t)v * CAP + j];
    for (int a = 1; a < cnt; ++a) {
        int key = idx[a];
        int b = a - 1;
        while (b >= 0 && idx[b] > key) { idx[b + 1] = idx[b]; --b; }
        idx[b + 1] = key;
    }
    int np = cnt < MAXP ? cnt : MAXP;
    num_out[v] = (float)np;
    for (int s = 0; s < np; ++s) {
        const float* p = pts + (size_t)idx[s] * 5;
        float* o = vox_out + ((size_t)v * MAXP + s) * 5;
        o[0] = p[0]; o[1] = p[1]; o[2] = p[2]; o[3] = p[3]; o[4] = p[4];
    }
}

// K5: exact fallback for >CAP-point voxels (expected empty): serial ordered rescan.
__global__ void k5_ovfl(const float* __restrict__ pts, int n,
                        const int* __restrict__ lin_arr,
                        const int* __restrict__ vcount,
                        const int* __restrict__ ovflCnt,
                        const int* __restrict__ ovflList,
                        const float* __restrict__ coors_out,
                        float* __restrict__ vox_out, float* __restrict__ num_out) {
    if (threadIdx.x != 0 || blockIdx.x != 0) return;
    int cnt = *ovflCnt;
    if (cnt > 1024) cnt = 1024;
    for (int e = 0; e < cnt; ++e) {
        int v = ovflList[e];
        int cx = (int)coors_out[(size_t)v * 3 + 0];
        int cy = (int)coors_out[(size_t)v * 3 + 1];
        int cz = (int)coors_out[(size_t)v * 3 + 2];
        int target = cx * GYZ + cy * GZD + cz;
        int found = 0;
        for (int i = 0; i < n && found < MAXP; ++i) {
            if (lin_arr[i] == target) {
                const float* p = pts + (size_t)i * 5;
                float* o = vox_out + ((size_t)v * MAXP + found) * 5;
                for (int c = 0; c < 5; ++c) o[c] = p[c];
                ++found;
            }
        }
        int np = vcount[v] < MAXP ? vcount[v] : MAXP;
        num_out[v] = (float)np;
    }
}

extern "C" void kernel_launch(void* const* d_in, const int* in_sizes, int n_in,
                              void* d_out, int out_size, void* d_ws, size_t ws_size,
                              hipStream_t stream) {
    const float* pts = (const float*)d_in[0];
    int n = in_sizes[0] / 5;
    int nb = (n + 255) / 256;
    int nb1 = nb < NB1CAP ? nb : NB1CAP;

    float* out = (float*)d_out;
    float* vox_out   = out;                       // [120000][10][5] = 6,000,000
    float* coors_out = out + 6000000;             // [120000][3]     =   360,000
    float* num_out   = out + 6360000;             // [120000]        =   120,000
    float* vn_out    = out + 6480000;             // scalar

    char* w = (char*)d_ws;
    unsigned long long* table = (unsigned long long*)w;  w += (size_t)HSIZE * 8; // 33.5 MB
    int* lin_arr   = (int*)w;               w += (size_t)n * 4;
    int* slot_arr  = (int*)w;               w += (size_t)n * 4;
    int* blockCnt  = (int*)w;               w += (size_t)nb * 4;
    int* blockOff  = (int*)w;               w += (size_t)nb * 4;
    int* vlist     = (int*)w;               w += (size_t)MAXV * CAP * 4;
    // zeroed region (one memset): flagWords + vcount + ovflCnt + meta
    unsigned long long* flagWords = (unsigned long long*)w; w += (size_t)nb * 4 * 8;
    int* vcount    = (int*)w;               w += (size_t)MAXV * 4;
    int* ovflCnt   = (int*)w;               w += 4;
    int* meta      = (int*)w;               w += 2 * 4;   // [total1, need2]
    int* ovflList  = (int*)w;               w += 1024 * 4;
    size_t zeroBytes = (size_t)nb * 4 * 8 + (size_t)MAXV * 4 + 4 + 8;

    hipMemsetAsync(d_out, 0, (size_t)out_size * 4, stream);
    hipMemsetAsync(table, 0xFF, (size_t)HSIZE * 8, stream);   // EMPTY64 sentinels
    hipMemsetAsync(flagWords, 0, zeroBytes, stream);

    k1_assign<<<nb, 256, 0, stream>>>(pts, n, lin_arr, slot_arr, table);
    k2a1_mark<<<nb1, 256, 0, stream>>>(n, slot_arr, table, flagWords, blockCnt);
    k2b1_scan<<<1, 256, 0, stream>>>(nb1, nb, blockCnt, blockOff, meta);
    if (nb > nb1) {
        k2a2_mark<<<nb - nb1, 256, 0, stream>>>(n, nb1, meta, slot_arr, table,
                                                flagWords, blockCnt);
    }
    k2b2_scan<<<1, 256, 0, stream>>>(nb, meta, blockCnt, blockOff, vn_out);
    k2c_rank<<<nb, 256, 0, stream>>>(n, lin_arr, slot_arr, flagWords, blockOff,
                                     table, coors_out);
    k3_append<<<nb, 256, 0, stream>>>(n, slot_arr, table, vcount, vlist);
    k4_emit<<<(MAXV + 255) / 256, 256, 0, stream>>>(pts, vcount, vlist, vox_out,
                                                    num_out, ovflCnt, ovflList);
    k5_ovfl<<<1, 64, 0, stream>>>(pts, n, lin_arr, vcount, ovflCnt, ovflList,
                                  coors_out, vox_out, num_out);
}